// Round 6
// baseline (303.407 us; speedup 1.0000x reference)
//
#include <hip/hip_runtime.h>

#define D_IN 33600
#define N1 1000
#define N2 4605
#define G1_CHUNKS 512    // balanced: block b covers rows [(b*33600)>>9, ((b+1)*33600)>>9)
#define NSCAL 307        // needed x2 scalars: index 15k+1, k=0..306
#define W2C_STRIDE 320   // padded col count of compact transpose
#define NT_BLOCKS 64     // transpose blocks appended to K1's grid
#define SEG1_JC 10       // seg1 j-chunks of 50 rows each

// K1': blocks [0,512) = partial GEMV1 (streams Wd1 134.4 MB, coalesced float4).
//      blocks [512,576) = gather the 307 needed Wd2 columns (j=15k+1) into
//      compact W2c[1000][320] so K4 can self-compute scalars without the
//      243 MB line-amplification that sank R4. Transpose depends on nothing,
//      so it rides in K1's dispatch shadow (+18.4 MB BW, ~+2.8 us).
__global__ __launch_bounds__(256) void k_gemv1_partial(
    const float* __restrict__ x, const float* __restrict__ Wd1,
    const float* __restrict__ Wd2, float* __restrict__ ws1, float* __restrict__ W2c) {
  const int b = blockIdx.x;
  const int t = threadIdx.x;
  if (b < G1_CHUNKS) {
    if (t >= 250) return;  // 250 * 4 = 1000 cols
    const int r0 = (b * D_IN) >> 9;
    const int r1 = ((b + 1) * D_IN) >> 9;
    const float* wp = Wd1 + (size_t)r0 * N1 + 4 * t;
    float ax = 0.f, ay = 0.f, az = 0.f, aw = 0.f;
#pragma unroll 8
    for (int i = 0; i < r1 - r0; ++i) {
      float4 w = *(const float4*)(wp + (size_t)i * N1);
      float xv = x[r0 + i];
      ax = fmaf(xv, w.x, ax);
      ay = fmaf(xv, w.y, ay);
      az = fmaf(xv, w.z, az);
      aw = fmaf(xv, w.w, aw);
    }
    *(float4*)(ws1 + (size_t)b * N1 + 4 * t) = make_float4(ax, ay, az, aw);
  } else {
    const int tb = b - G1_CHUNKS;               // 0..63
    const int r0 = (tb * N1) >> 6;
    const int r1 = ((tb + 1) * N1) >> 6;
    for (int r = r0; r < r1; ++r) {
      const float* src = Wd2 + (size_t)r * N2;
      float* dst = W2c + (size_t)r * W2C_STRIDE;
      for (int k = t; k < NSCAL; k += 256) dst[k] = src[15 * k + 1];
    }
  }
}

// K2 (line-coalesced): block b reduces cols [16b, 16b+16). 16 consecutive lanes
// read 16 consecutive floats = exactly one 64B line; each ws1 line fetched once.
__global__ __launch_bounds__(256) void k_reduce1(
    const float* __restrict__ ws1, const float* __restrict__ bd1, float* __restrict__ x1) {
  const int c0 = blockIdx.x * 16;
  const int t = threadIdx.x;
  const int cl = t & 15;
  const int ch0 = t >> 4;  // 0..15
  const int c = c0 + cl;
  float s = 0.f;
  if (c < N1) {
#pragma unroll 8
    for (int ch = ch0; ch < G1_CHUNKS; ch += 16)  // 32 iterations
      s += ws1[(size_t)ch * N1 + c];
  }
  __shared__ float red[16][16];
  red[ch0][cl] = s;
  __syncthreads();
  if (t < 16 && c0 + t < N1) {
    float sum = 0.f;
#pragma unroll
    for (int i = 0; i < 16; ++i) sum += red[i][t];
    x1[c0 + t] = fmaxf(sum + bd1[c0 + t], 0.f);
  }
}

// K4: all 4 hypernet segments; each block self-computes its <=16 scalars from
// compact W2c (16 consecutive floats/row = 1 line; ~64KB/block, L2-resident).
// Block roles (253 total):
//   [0,210)   seg1: 21 col tiles x 10 j-chunks(50) -> raw partials to ws3
//   [210,214) seg2: 2 groups x 2 tiles             -> out (bias+relu)
//   [214,246) seg3: 16 groups x 2 tiles            -> out
//   [246,253) seg4: 1 group (3 scalars) x 7 tiles  -> out
__global__ __launch_bounds__(256) void k_segments(
    const float* __restrict__ x1, const float* __restrict__ W2c, const float* __restrict__ bd2,
    const float* __restrict__ W1a, const float* __restrict__ b1a, const float* __restrict__ W1b,
    const float* __restrict__ W2a, const float* __restrict__ b2a,
    const float* __restrict__ W2b, const float* __restrict__ b2b,
    const float* __restrict__ W3a, const float* __restrict__ b3a,
    const float* __restrict__ W3b, const float* __restrict__ b3b,
    const float* __restrict__ W4a, const float* __restrict__ b4a,
    const float* __restrict__ W4b, const float* __restrict__ b4b,
    float* __restrict__ ws3, float* __restrict__ out) {
  __shared__ float xh[N1];
  __shared__ float sScal[16];
  __shared__ float sH[100 * 16];
  __shared__ float sRed[4][16];
  const int b = blockIdx.x;
  const int t = threadIdx.x;

  const float *Wa, *ba, *Wb, *bb = nullptr;
  int outn, colbase, jbase = 0, jcount, k0, kn;
  float* dst;
  int dst_stride;
  bool raw;

  if (b < 210) {
    const int tile = b % 21, chunk = b / 21;
    Wa = W1a; ba = b1a; Wb = W1b;
    outn = 5121; colbase = tile * 256; jbase = chunk * 50; jcount = 50;
    k0 = 0; kn = 16;
    dst = ws3 + (size_t)chunk * 16 * 5121; dst_stride = 5121; raw = true;
  } else if (b < 214) {
    const int r = b - 210, g = r >> 1, tile = r & 1;
    Wa = W2a; ba = b2a; Wb = W2b; bb = b2b;
    outn = 257; colbase = tile * 256; jcount = 100;
    k0 = 16 + g * 16; kn = 16;
    dst = out + 81936 + (size_t)g * 16 * 257; dst_stride = 257; raw = false;
  } else if (b < 246) {
    const int r = b - 214, g = r >> 1, tile = r & 1;
    Wa = W3a; ba = b3a; Wb = W3b; bb = b3b;
    outn = 321; colbase = tile * 256; jcount = 100;
    k0 = 48 + g * 16; kn = 16;
    dst = out + 90160 + (size_t)g * 16 * 321; dst_stride = 321; raw = false;
  } else {
    const int tile = b - 246;
    Wa = W4a; ba = b4a; Wb = W4b; bb = b4b;
    outn = 1542; colbase = tile * 256; jcount = 100;
    k0 = 304; kn = 3;
    dst = out + 172336; dst_stride = 1542; raw = false;
  }

  // Stage x1 into LDS (4KB, coalesced, L2-hot).
  for (int r = t; r < N1; r += 256) xh[r] = x1[r];
  __syncthreads();

  // Scalars: thread (k=t&15, l=t>>4) accumulates rows r=l, l+16, ...
  // Lanes 0..15 read 16 consecutive W2c floats of one row = one 64B line.
  {
    const int k = t & 15, l = t >> 4;
    float s = 0.f;
    if (k < kn) {
      const float* wp = W2c + (k0 + k);
      for (int r = l; r < N1; r += 16)
        s = fmaf(xh[r], wp[(size_t)r * W2C_STRIDE], s);
    }
    s += __shfl_xor(s, 16, 64);  // sum 4 l-values within wave
    s += __shfl_xor(s, 32, 64);
    if ((t & 63) < 16) sRed[t >> 6][k] = s;
  }
  __syncthreads();
  if (t < 16) {
    float sum = sRed[0][t] + sRed[1][t] + sRed[2][t] + sRed[3][t];
    sScal[t] = (t < kn) ? fmaxf(sum + bd2[15 * (k0 + t) + 1], 0.f) : 0.f;
  }
  __syncthreads();

  // h-table: sH[j*16 + k] = relu(sScal[k]*Wa[j] + ba[j]).
  for (int e = t; e < jcount * 16; e += 256) {
    const int j = e >> 4, kk = e & 15;
    float hv = 0.f;
    if (kk < kn) hv = fmaxf(fmaf(sScal[kk], Wa[jbase + j], ba[jbase + j]), 0.f);
    sH[e] = hv;
  }
  __syncthreads();

  const int m = colbase + t;
  if (m < outn) {
    float acc[16];
#pragma unroll
    for (int k = 0; k < 16; ++k) acc[k] = 0.f;
    const float* wb = Wb + (size_t)jbase * outn + m;
    for (int j = 0; j < jcount; ++j) {
      const float w = wb[(size_t)j * outn];   // coalesced across lanes
      const float4* hp = (const float4*)(sH + j * 16);  // broadcast reads
      const float4 h0 = hp[0], h1 = hp[1], h2 = hp[2], h3 = hp[3];
      acc[0]  = fmaf(h0.x, w, acc[0]);   acc[1]  = fmaf(h0.y, w, acc[1]);
      acc[2]  = fmaf(h0.z, w, acc[2]);   acc[3]  = fmaf(h0.w, w, acc[3]);
      acc[4]  = fmaf(h1.x, w, acc[4]);   acc[5]  = fmaf(h1.y, w, acc[5]);
      acc[6]  = fmaf(h1.z, w, acc[6]);   acc[7]  = fmaf(h1.w, w, acc[7]);
      acc[8]  = fmaf(h2.x, w, acc[8]);   acc[9]  = fmaf(h2.y, w, acc[9]);
      acc[10] = fmaf(h2.z, w, acc[10]);  acc[11] = fmaf(h2.w, w, acc[11]);
      acc[12] = fmaf(h3.x, w, acc[12]);  acc[13] = fmaf(h3.y, w, acc[13]);
      acc[14] = fmaf(h3.z, w, acc[14]);  acc[15] = fmaf(h3.w, w, acc[15]);
    }
    if (raw) {
#pragma unroll
      for (int k = 0; k < 16; ++k) dst[(size_t)k * dst_stride + m] = acc[k];
    } else {
      const float bv = bb[m];
      for (int k = 0; k < kn; ++k)
        dst[(size_t)k * dst_stride + m] = fmaxf(acc[k] + bv, 0.f);
    }
  }
}

// K5: seg1 finalize: sum 10 j-chunk partials + bias, relu -> out[0..81936).
__global__ __launch_bounds__(256) void k_final_seg1(
    const float* __restrict__ ws3, const float* __restrict__ b1b, float* __restrict__ out) {
  const int i = blockIdx.x * 256 + threadIdx.x;
  if (i >= 16 * 5121) return;
  const int k = i / 5121;
  const int m = i - k * 5121;
  float s = b1b[m];
#pragma unroll
  for (int c = 0; c < SEG1_JC; ++c) s += ws3[((size_t)c * 16 + k) * 5121 + m];
  out[i] = fmaxf(s, 0.f);
}

extern "C" void kernel_launch(void* const* d_in, const int* in_sizes, int n_in,
                              void* d_out, int out_size, void* d_ws, size_t ws_size,
                              hipStream_t stream) {
  const float* x   = (const float*)d_in[0];
  const float* Wd1 = (const float*)d_in[1];
  const float* bd1 = (const float*)d_in[2];
  const float* Wd2 = (const float*)d_in[3];
  const float* bd2 = (const float*)d_in[4];
  const float* W1a = (const float*)d_in[5];
  const float* b1a = (const float*)d_in[6];
  const float* W1b = (const float*)d_in[7];
  const float* b1b = (const float*)d_in[8];
  const float* W2a = (const float*)d_in[9];
  const float* b2a = (const float*)d_in[10];
  const float* W2b = (const float*)d_in[11];
  const float* b2b = (const float*)d_in[12];
  const float* W3a = (const float*)d_in[13];
  const float* b3a = (const float*)d_in[14];
  const float* W3b = (const float*)d_in[15];
  const float* b3b = (const float*)d_in[16];
  const float* W4a = (const float*)d_in[17];
  const float* b4a = (const float*)d_in[18];
  const float* W4b = (const float*)d_in[19];
  const float* b4b = (const float*)d_in[20];
  float* out = (float*)d_out;

  float* ws  = (float*)d_ws;
  float* ws1 = ws;                         // 512 * 1000
  float* x1  = ws1 + G1_CHUNKS * N1;       // 1000 (pad to 1024)
  float* W2c = x1 + 1024;                  // 1000 * 320
  float* ws3 = W2c + N1 * W2C_STRIDE;      // 10 * 16 * 5121

  hipLaunchKernelGGL(k_gemv1_partial, dim3(G1_CHUNKS + NT_BLOCKS), dim3(256), 0, stream,
                     x, Wd1, Wd2, ws1, W2c);
  hipLaunchKernelGGL(k_reduce1, dim3((N1 + 15) / 16), dim3(256), 0, stream, ws1, bd1, x1);
  hipLaunchKernelGGL(k_segments, dim3(253), dim3(256), 0, stream,
                     x1, W2c, bd2, W1a, b1a, W1b, W2a, b2a, W2b, b2b,
                     W3a, b3a, W3b, b3b, W4a, b4a, W4b, b4b, ws3, out);
  hipLaunchKernelGGL(k_final_seg1, dim3((16 * 5121 + 255) / 256), dim3(256), 0, stream,
                     ws3, b1b, out);
}

// Round 7
// 279.184 us; speedup vs baseline: 1.0868x; 1.0868x over previous
//
#include <hip/hip_runtime.h>

#define D_IN 33600
#define N1 1000
#define N2 4605
#define G1_CHUNKS 512    // balanced: block b covers rows [(b*33600)>>9, ((b+1)*33600)>>9)
#define NSCAL 307        // needed x2 scalars: index 15k+1, k=0..306
#define SEG1_JC 10       // seg1 j-chunks of 50 rows each

// K1: partial GEMV1. Block = balanced row chunk; thread t handles 4 cols (float4).
// Streams Wd1 (134.4 MB) once, coalesced 16B/lane -> HBM-bound (~20 us).
// NOTE (R3/R4/R6): do NOT fold later phases into this dispatch. grid.sync
// (R3: +127us), per-block scalar recompute (R4: +26us via 60B-stride line
// amplification), and a transpose rider (R6: +20us latency-bound gather tail)
// all regressed. Plain stream-ordered small dispatches win on this chip.
__global__ __launch_bounds__(256) void k_gemv1_partial(
    const float* __restrict__ x, const float* __restrict__ Wd1, float* __restrict__ ws1) {
  const int chunk = blockIdx.x;
  const int t = threadIdx.x;
  if (t >= 250) return;  // 250 * 4 = 1000 cols
  const int r0 = (chunk * D_IN) >> 9;
  const int r1 = ((chunk + 1) * D_IN) >> 9;
  const float* wp = Wd1 + (size_t)r0 * N1 + 4 * t;
  float ax = 0.f, ay = 0.f, az = 0.f, aw = 0.f;
#pragma unroll 8
  for (int i = 0; i < r1 - r0; ++i) {
    float4 w = *(const float4*)(wp + (size_t)i * N1);
    float xv = x[r0 + i];
    ax = fmaf(xv, w.x, ax);
    ay = fmaf(xv, w.y, ay);
    az = fmaf(xv, w.z, az);
    aw = fmaf(xv, w.w, aw);
  }
  *(float4*)(ws1 + (size_t)chunk * N1 + 4 * t) = make_float4(ax, ay, az, aw);
}

// K2 (line-coalesced): block b reduces cols [16b, 16b+16). 16 consecutive lanes
// read 16 consecutive floats = exactly one 64B line; each ws1 line fetched once.
__global__ __launch_bounds__(256) void k_reduce1(
    const float* __restrict__ ws1, const float* __restrict__ bd1, float* __restrict__ x1) {
  const int c0 = blockIdx.x * 16;
  const int t = threadIdx.x;
  const int cl = t & 15;
  const int ch0 = t >> 4;  // 0..15
  const int c = c0 + cl;
  float s = 0.f;
  if (c < N1) {
#pragma unroll 8
    for (int ch = ch0; ch < G1_CHUNKS; ch += 16)  // 32 iterations
      s += ws1[(size_t)ch * N1 + c];
  }
  __shared__ float red[16][16];
  red[ch0][cl] = s;
  __syncthreads();
  if (t < 16 && c0 + t < N1) {
    float sum = 0.f;
#pragma unroll
    for (int i = 0; i < 16; ++i) sum += red[i][t];
    x1[c0 + t] = fmaxf(sum + bd1[c0 + t], 0.f);
  }
}

// K3: only the 307 consumed x2 scalars. Block k computes
// sS[k] = relu(dot(x1, Wd2[:, 15k+1]) + bd2[15k+1]).
__global__ __launch_bounds__(256) void k_scalars(
    const float* __restrict__ x1, const float* __restrict__ Wd2,
    const float* __restrict__ bd2, float* __restrict__ sS) {
  const int k = blockIdx.x;
  const int t = threadIdx.x;
  const int j = 15 * k + 1;
  float s = 0.f;
#pragma unroll 4
  for (int r = t; r < N1; r += 256) s = fmaf(x1[r], Wd2[(size_t)r * N2 + j], s);
#pragma unroll
  for (int off = 32; off > 0; off >>= 1) s += __shfl_down(s, off, 64);
  __shared__ float red[4];
  if ((t & 63) == 0) red[t >> 6] = s;
  __syncthreads();
  if (t == 0) sS[k] = fmaxf(red[0] + red[1] + red[2] + red[3] + bd2[j], 0.f);
}

// K4: all 4 hypernet segments. Each block: 16-scalar group, j-chunk, <=256 out-cols.
// h-table (jcount x 16) in LDS; 16 acc/thread.
// Block roles (253 total):
//   [0,210)   seg1: 21 col tiles x 10 j-chunks(50) -> raw partials to ws3
//   [210,214) seg2: 2 groups x 2 tiles             -> out (bias+relu)
//   [214,246) seg3: 16 groups x 2 tiles            -> out
//   [246,253) seg4: 1 group (3 scalars) x 7 tiles  -> out
__global__ __launch_bounds__(256) void k_segments(
    const float* __restrict__ sS,
    const float* __restrict__ W1a, const float* __restrict__ b1a, const float* __restrict__ W1b,
    const float* __restrict__ W2a, const float* __restrict__ b2a,
    const float* __restrict__ W2b, const float* __restrict__ b2b,
    const float* __restrict__ W3a, const float* __restrict__ b3a,
    const float* __restrict__ W3b, const float* __restrict__ b3b,
    const float* __restrict__ W4a, const float* __restrict__ b4a,
    const float* __restrict__ W4b, const float* __restrict__ b4b,
    float* __restrict__ ws3, float* __restrict__ out) {
  __shared__ float sHs[16];
  __shared__ float sH[100 * 16];
  const int b = blockIdx.x;
  const int t = threadIdx.x;

  const float *Wa, *ba, *Wb, *bb = nullptr;
  int outn, colbase, jbase = 0, jcount, k0, kn;
  float* dst;
  int dst_stride;
  bool raw;

  if (b < 210) {
    const int tile = b % 21, chunk = b / 21;
    Wa = W1a; ba = b1a; Wb = W1b;
    outn = 5121; colbase = tile * 256; jbase = chunk * 50; jcount = 50;
    k0 = 0; kn = 16;
    dst = ws3 + (size_t)chunk * 16 * 5121; dst_stride = 5121; raw = true;
  } else if (b < 214) {
    const int r = b - 210, g = r >> 1, tile = r & 1;
    Wa = W2a; ba = b2a; Wb = W2b; bb = b2b;
    outn = 257; colbase = tile * 256; jcount = 100;
    k0 = 16 + g * 16; kn = 16;
    dst = out + 81936 + (size_t)g * 16 * 257; dst_stride = 257; raw = false;
  } else if (b < 246) {
    const int r = b - 214, g = r >> 1, tile = r & 1;
    Wa = W3a; ba = b3a; Wb = W3b; bb = b3b;
    outn = 321; colbase = tile * 256; jcount = 100;
    k0 = 48 + g * 16; kn = 16;
    dst = out + 90160 + (size_t)g * 16 * 321; dst_stride = 321; raw = false;
  } else {
    const int tile = b - 246;
    Wa = W4a; ba = b4a; Wb = W4b; bb = b4b;
    outn = 1542; colbase = tile * 256; jcount = 100;
    k0 = 304; kn = 3;
    dst = out + 172336; dst_stride = 1542; raw = false;
  }

  if (t < 16) sHs[t] = (t < kn) ? sS[k0 + t] : 0.f;
  __syncthreads();

  for (int e = t; e < jcount * 16; e += 256) {
    const int j = e >> 4, k = e & 15;
    float hv = 0.f;
    if (k < kn) hv = fmaxf(fmaf(sHs[k], Wa[jbase + j], ba[jbase + j]), 0.f);
    sH[e] = hv;  // layout: sH[j*16 + k]
  }
  __syncthreads();

  const int m = colbase + t;
  if (m < outn) {
    float acc[16];
#pragma unroll
    for (int k = 0; k < 16; ++k) acc[k] = 0.f;
    const float* wb = Wb + (size_t)jbase * outn + m;
    for (int j = 0; j < jcount; ++j) {
      const float w = wb[(size_t)j * outn];   // coalesced across lanes
      const float4* hp = (const float4*)(sH + j * 16);  // broadcast reads
      const float4 h0 = hp[0], h1 = hp[1], h2 = hp[2], h3 = hp[3];
      acc[0]  = fmaf(h0.x, w, acc[0]);   acc[1]  = fmaf(h0.y, w, acc[1]);
      acc[2]  = fmaf(h0.z, w, acc[2]);   acc[3]  = fmaf(h0.w, w, acc[3]);
      acc[4]  = fmaf(h1.x, w, acc[4]);   acc[5]  = fmaf(h1.y, w, acc[5]);
      acc[6]  = fmaf(h1.z, w, acc[6]);   acc[7]  = fmaf(h1.w, w, acc[7]);
      acc[8]  = fmaf(h2.x, w, acc[8]);   acc[9]  = fmaf(h2.y, w, acc[9]);
      acc[10] = fmaf(h2.z, w, acc[10]);  acc[11] = fmaf(h2.w, w, acc[11]);
      acc[12] = fmaf(h3.x, w, acc[12]);  acc[13] = fmaf(h3.y, w, acc[13]);
      acc[14] = fmaf(h3.z, w, acc[14]);  acc[15] = fmaf(h3.w, w, acc[15]);
    }
    if (raw) {
#pragma unroll
      for (int k = 0; k < 16; ++k) dst[(size_t)k * dst_stride + m] = acc[k];
    } else {
      const float bv = bb[m];
      for (int k = 0; k < kn; ++k)
        dst[(size_t)k * dst_stride + m] = fmaxf(acc[k] + bv, 0.f);
    }
  }
}

// K5: seg1 finalize: sum 10 j-chunk partials + bias, relu -> out[0..81936).
__global__ __launch_bounds__(256) void k_final_seg1(
    const float* __restrict__ ws3, const float* __restrict__ b1b, float* __restrict__ out) {
  const int i = blockIdx.x * 256 + threadIdx.x;
  if (i >= 16 * 5121) return;
  const int k = i / 5121;
  const int m = i - k * 5121;
  float s = b1b[m];
#pragma unroll
  for (int c = 0; c < SEG1_JC; ++c) s += ws3[((size_t)c * 16 + k) * 5121 + m];
  out[i] = fmaxf(s, 0.f);
}

extern "C" void kernel_launch(void* const* d_in, const int* in_sizes, int n_in,
                              void* d_out, int out_size, void* d_ws, size_t ws_size,
                              hipStream_t stream) {
  const float* x   = (const float*)d_in[0];
  const float* Wd1 = (const float*)d_in[1];
  const float* bd1 = (const float*)d_in[2];
  const float* Wd2 = (const float*)d_in[3];
  const float* bd2 = (const float*)d_in[4];
  const float* W1a = (const float*)d_in[5];
  const float* b1a = (const float*)d_in[6];
  const float* W1b = (const float*)d_in[7];
  const float* b1b = (const float*)d_in[8];
  const float* W2a = (const float*)d_in[9];
  const float* b2a = (const float*)d_in[10];
  const float* W2b = (const float*)d_in[11];
  const float* b2b = (const float*)d_in[12];
  const float* W3a = (const float*)d_in[13];
  const float* b3a = (const float*)d_in[14];
  const float* W3b = (const float*)d_in[15];
  const float* b3b = (const float*)d_in[16];
  const float* W4a = (const float*)d_in[17];
  const float* b4a = (const float*)d_in[18];
  const float* W4b = (const float*)d_in[19];
  const float* b4b = (const float*)d_in[20];
  float* out = (float*)d_out;

  float* ws  = (float*)d_ws;
  float* ws1 = ws;                         // 512 * 1000
  float* x1  = ws1 + G1_CHUNKS * N1;       // 1000 (pad to 1024)
  float* sS  = x1 + 1024;                  // 307 (pad to 512)
  float* ws3 = sS + 512;                   // 10 * 16 * 5121

  hipLaunchKernelGGL(k_gemv1_partial, dim3(G1_CHUNKS), dim3(256), 0, stream, x, Wd1, ws1);
  hipLaunchKernelGGL(k_reduce1, dim3((N1 + 15) / 16), dim3(256), 0, stream, ws1, bd1, x1);
  hipLaunchKernelGGL(k_scalars, dim3(NSCAL), dim3(256), 0, stream, x1, Wd2, bd2, sS);
  hipLaunchKernelGGL(k_segments, dim3(253), dim3(256), 0, stream,
                     sS, W1a, b1a, W1b, W2a, b2a, W2b, b2b,
                     W3a, b3a, W3b, b3b, W4a, b4a, W4b, b4b, ws3, out);
  hipLaunchKernelGGL(k_final_seg1, dim3((16 * 5121 + 255) / 256), dim3(256), 0, stream,
                     ws3, b1b, out);
}